// Round 6
// baseline (5519.803 us; speedup 1.0000x reference)
//
#include <hip/hip_runtime.h>
#include <hip/hip_bf16.h>
#include <hip/hip_cooperative_groups.h>
#include <math.h>

namespace cg = cooperative_groups;

// Problem constants
#define NN      1500
#define NEE     1200
#define NPAD    1536
#define BATCH   96
#define NSTEP   60
#define PI_F    3.14159265358979323846f

// geometry: 192 WGs = 96 i-tiles (16) x 2 batch-halves (48); 512 thr (8 waves)
#define NWG     192
#define NTHR    512
#define WAVES   8
#define KSLW    (NPAD / WAVES) // 192 = 6 MFMA k-steps of 32
#define BH      48             // batch-half size
#define MFR     3              // m fragments per wave (48/16)

// LDS reduce: 8 slots x [2 outs][16 i][49 pad-b] f32 = 50176 B
#define BP      49
#define SLOTF   (2 * 16 * BP)  // 1568 floats
#define LDS_BYTES 90112        // > 50176; forces 1 WG/CU (2x would exceed 160 KiB)

typedef __attribute__((ext_vector_type(8))) short short8b;  // 8 bf16
typedef __attribute__((ext_vector_type(4))) float f32x4;    // MFMA acc

// ---------------- bf16 split helpers ----------------------------------------

__device__ __forceinline__ ushort bf16_rn(float x) {
    unsigned u = __float_as_uint(x);
    unsigned r = (u + 0x7FFFu + ((u >> 16) & 1u)) >> 16;
    return (ushort)r;
}
__device__ __forceinline__ float bf16f(ushort h) {
    return __uint_as_float(((unsigned)h) << 16);
}

// ---------------- phi (Ricciardi LIF transfer) ------------------------------

__device__ __forceinline__ float f_ricci(float x) {
    float z = x / (1.0f + x);
    float t = -z;
    float p = 0.14805913578876898f;
    p = p * t + 0.64290613877355551f;
    p = p * t + 1.0616084849547165f;
    p = p * t + 0.93524391761244940f;
    p = p * t + 0.62718906618071668f;
    p = p * t + 0.32171431660633076f;
    p = p * t + 0.32056016125642045f;
    p = p * t + 0.77373949685442023f;
    p = p * t + 0.22757881388024176f;
    p = p * t;
    return logf(2.0f * x + 1.0f) + p;
}

__device__ __forceinline__ float g_ricci(float x) {
    float z = x / (2.0f + x);
    float num = z * (3.5441754117462949f + z * (-7.0529131065835378f + z * (-56.532378057580381f
        + z * (279.56761105465944f + z * (-520.37554849441472f + z * (456.58245777026514f
        + z * (-155.73340457809226f)))))));
    float den = 1.0f + z * (-4.1357968834226053f + z * (-7.2984226138266743f + z * (98.656602235468327f
        + z * (-334.20436223415163f + z * (601.08633903294185f + z * (-599.58577549598340f
        + z * (277.18420330693891f + z * (-16.445022798669722f))))))));
    return num / den;
}

__device__ __forceinline__ float phi_lif(float mu, float sig, float tau, float tau_ref) {
    float xp = mu / sig;
    float xm = (mu - 20.0f) / sig;
    float r0;
    if (xm > 0.0f) {
        r0 = 1.0f / (f_ricci(xp) - f_ricci(xm));
    } else if (xp > 0.0f) {
        r0 = 1.0f / (f_ricci(xp) + expf(xm * xm) * g_ricci(-xm));
    } else {
        float a = g_ricci(-xm) - expf(xp * xp - xm * xm) * g_ricci(-xp);
        r0 = expf(-xm * xm - logf(a));
    }
    r0 = fmaxf(r0, 1e-30f);
    return 1.0f / (tau_ref + tau / r0);
}

__device__ __forceinline__ float pref_of(int n) {
    const float stepE = 179.99f / 1200.0f;
    const float stepI = 179.99f / 300.0f;
    return (n < NEE) ? (float)n * stepE : (float)(n - NEE) * stepI;
}

// ---------------- kernel 1: build bf16-split weight planes [i][k] -----------

__global__ __launch_bounds__(256) void k_weights(const float* __restrict__ hyp,
        const float* __restrict__ rand_mat,
        ushort* __restrict__ Whi, ushort* __restrict__ Wlo,
        ushort* __restrict__ W2hi, ushort* __restrict__ W2lo) {
    int k = blockIdx.x * 256 + threadIdx.x;   // source neuron (contiguous)
    int i = blockIdx.y;                        // dest neuron
    size_t idx = (size_t)i * NPAD + k;
    if (i >= NN || k >= NN) {
        Whi[idx] = 0; Wlo[idx] = 0; W2hi[idx] = 0; W2lo[idx] = 0;
        return;
    }
    float diff = fabsf(pref_of(i) - pref_of(k));
    int conn = (i >= NEE ? 1 : 0) + 2 * (k >= NEE ? 1 : 0);
    float J  = hyp[conn];
    float P  = hyp[4 + conn];
    float Wp = hyp[8 + conn];
    float dn = 4.0f * (PI_F / 180.0f * Wp) * (PI_F / 180.0f * Wp);
    float z = expf((cosf(2.0f * PI_F / 180.0f * diff) - 1.0f) / dn);
    float x = 32.0f * (P * z - rand_mat[(size_t)i * NN + k]);
    float w = J / (1.0f + expf(-x));
    float w2 = w * w;
    ushort h = bf16_rn(w);
    Whi[idx] = h;  Wlo[idx] = bf16_rn(w - bf16f(h));
    ushort h2 = bf16_rn(w2);
    W2hi[idx] = h2; W2lo[idx] = bf16_rn(w2 - bf16f(h2));
}

// ---------------- kernel 2: all 60 steps, cooperative, fused ----------------
// WG (it,bhf): 16 i x 48 b block. Waves split K (192 each); one-barrier LDS
// reduce; phi + Euler with rate/mean in REGISTERS; only bf16 rate planes
// (1.2 MB/step) cross the grid barrier, double-buffered A/B.

__global__ __launch_bounds__(NTHR) void k_coop(
        const ushort* __restrict__ Whi, const ushort* __restrict__ Wlo,
        const ushort* __restrict__ W2hi, const ushort* __restrict__ W2lo,
        ushort* __restrict__ rhiA, ushort* __restrict__ rloA,
        ushort* __restrict__ rhiB, ushort* __restrict__ rloB,
        float* __restrict__ out)
{
    cg::grid_group grid = cg::this_grid();
    extern __shared__ float sm[];

    const int tid  = threadIdx.x;
    const int wave = tid >> 6;
    const int lane = tid & 63;
    const int lr   = lane & 15;
    const int lq   = lane >> 4;
    const int bx   = blockIdx.x;
    // XCD swizzle (xcd = bx % 8 round-robin): both halves of an i-tile and 12
    // consecutive i-tiles land on one XCD -> 2.4 MB weight slice stays L2-local.
    const int it   = (bx & 7) * 12 + (bx >> 4);
    const int bhf  = (bx >> 3) & 1;
    const int i0   = it * 16;
    const int b0   = bhf * BH;
    const int kb   = wave * KSLW;

    // ---- per-thread update-element state (e = b*16 + c), rate in registers --
    const int e0 = tid;              // < 768 always
    const int c0 = e0 & 15, bb0 = e0 >> 4;
    const int ig0 = i0 + c0, gb0 = b0 + bb0;
    const size_t gx0 = (size_t)gb0 * NPAD + ig0;
    const bool has1 = (tid < BH * 16 - NTHR);   // tid < 256
    const int e1 = tid + NTHR;
    const int c1 = e1 & 15, bb1 = e1 >> 4;
    const int ig1 = i0 + c1, gb1 = b0 + bb1;
    const size_t gx1 = (size_t)gb1 * NPAD + ig1;

    const float contrasts[8] = {0.0f, 0.0432773f, 0.103411f, 0.186966f,
                                0.303066f, 0.464386f, 0.68854f, 1.0f};
    const float dnff = 4.0f * (PI_F / 180.0f * 30.0f) * (PI_F / 180.0f * 30.0f);
    float mean0 = 0.0f, mean1 = 0.0f;
    if (ig0 < NN) {
        float dth = 15.0f * (float)(gb0 % 12) - pref_of(ig0);
        mean0 = contrasts[gb0 / 12] * 20.0f *
                expf((cosf(2.0f * PI_F / 180.0f * dth) - 1.0f) / dnff);
    }
    if (has1 && ig1 < NN) {
        float dth = 15.0f * (float)(gb1 % 12) - pref_of(ig1);
        mean1 = contrasts[gb1 / 12] * 20.0f *
                expf((cosf(2.0f * PI_F / 180.0f * dth) - 1.0f) / dnff);
    }
    float rr0 = 0.0f, rr1 = 0.0f;

    // zero initial (A) planes for this WG's block
    rhiA[gx0] = 0; rloA[gx0] = 0;
    if (has1) { rhiA[gx1] = 0; rloA[gx1] = 0; }

    __threadfence();
    grid.sync();
    __threadfence();

    const size_t bof = (size_t)(i0 + lr) * NPAD + kb + lq * 8;

    for (int s = 0; s < NSTEP; s++) {
        const ushort* rin_hi = (s & 1) ? rhiB : rhiA;
        const ushort* rin_lo = (s & 1) ? rloB : rloA;
        ushort* rout_hi = (s & 1) ? rhiA : rhiB;
        ushort* rout_lo = (s & 1) ? rloA : rloB;

        f32x4 acc1[MFR], acc2[MFR];
#pragma unroll
        for (int m = 0; m < MFR; m++) {
            acc1[m] = (f32x4){0.0f, 0.0f, 0.0f, 0.0f};
            acc2[m] = (f32x4){0.0f, 0.0f, 0.0f, 0.0f};
        }

#pragma unroll 2
        for (int kk = 0; kk < KSLW / 32; kk++) {
            const int ko = kk * 32;
            short8b wh  = *(const short8b*)(Whi  + bof + ko);
            short8b wl  = *(const short8b*)(Wlo  + bof + ko);
            short8b w2h = *(const short8b*)(W2hi + bof + ko);
            short8b w2l = *(const short8b*)(W2lo + bof + ko);
#pragma unroll
            for (int m = 0; m < MFR; m++) {
                const size_t aof = (size_t)(b0 + m * 16 + lr) * NPAD + kb + lq * 8 + ko;
                short8b ah = *(const short8b*)(rin_hi + aof);
                short8b al = *(const short8b*)(rin_lo + aof);
                // 3-pass split (identical numerics to rounds 4/5)
                acc1[m] = __builtin_amdgcn_mfma_f32_16x16x32_bf16(ah, wh,  acc1[m], 0, 0, 0);
                acc1[m] = __builtin_amdgcn_mfma_f32_16x16x32_bf16(ah, wl,  acc1[m], 0, 0, 0);
                acc1[m] = __builtin_amdgcn_mfma_f32_16x16x32_bf16(al, wh,  acc1[m], 0, 0, 0);
                acc2[m] = __builtin_amdgcn_mfma_f32_16x16x32_bf16(ah, w2h, acc2[m], 0, 0, 0);
                acc2[m] = __builtin_amdgcn_mfma_f32_16x16x32_bf16(ah, w2l, acc2[m], 0, 0, 0);
                acc2[m] = __builtin_amdgcn_mfma_f32_16x16x32_bf16(al, w2h, acc2[m], 0, 0, 0);
            }
        }

        // ---- dump to own LDS slot; C/D map: col(i)=lr, row(b in frag)=4*lq+r
        {
            float* sp = sm + wave * SLOTF;
#pragma unroll
            for (int m = 0; m < MFR; m++) {
                float* p1 = sp + lr * BP + m * 16 + 4 * lq;
                float* p2 = p1 + 16 * BP;
                *(f32x4*)p1 = acc1[m];
                *(f32x4*)p2 = acc2[m];
            }
        }
        __syncthreads();

        // ---- reduce 8 slots + phi + Euler (registers) + write next planes --
        {
            float rn = 0.0f;
            if (ig0 < NN) {
                float u1 = 0.0f, u2 = 0.0f;
#pragma unroll
                for (int w = 0; w < WAVES; w++) {
                    u1 += sm[w * SLOTF + c0 * BP + bb0];
                    u2 += sm[w * SLOTF + (16 + c0) * BP + bb0];
                }
                float mu = 0.01f * u1 + mean0;
                float sg = sqrtf(0.01f * u2 + 25.0f);
                float tr = (ig0 < NEE) ? 0.005f : 0.001f;
                float Ti = (ig0 < NEE) ? 100.0f : 200.0f;
                float ph = phi_lif(mu, sg, 0.01f, tr);
                rr0 = rr0 + 1e-3f * Ti * (ph - rr0);
                rn = rr0;
                if (s == NSTEP - 1) out[(size_t)ig0 * BATCH + gb0] = rn;
            }
            ushort h = bf16_rn(rn);
            rout_hi[gx0] = h;
            rout_lo[gx0] = bf16_rn(rn - bf16f(h));
        }
        if (has1) {
            float rn = 0.0f;
            if (ig1 < NN) {
                float u1 = 0.0f, u2 = 0.0f;
#pragma unroll
                for (int w = 0; w < WAVES; w++) {
                    u1 += sm[w * SLOTF + c1 * BP + bb1];
                    u2 += sm[w * SLOTF + (16 + c1) * BP + bb1];
                }
                float mu = 0.01f * u1 + mean1;
                float sg = sqrtf(0.01f * u2 + 25.0f);
                float tr = (ig1 < NEE) ? 0.005f : 0.001f;
                float Ti = (ig1 < NEE) ? 100.0f : 200.0f;
                float ph = phi_lif(mu, sg, 0.01f, tr);
                rr1 = rr1 + 1e-3f * Ti * (ph - rr1);
                rn = rr1;
                if (s == NSTEP - 1) out[(size_t)ig1 * BATCH + gb1] = rn;
            }
            ushort h = bf16_rn(rn);
            rout_hi[gx1] = h;
            rout_lo[gx1] = bf16_rn(rn - bf16f(h));
        }
        __syncthreads();          // LDS reuse next iteration
        __threadfence();          // release: plane writes -> coherence point
        grid.sync();
        __threadfence();          // acquire: invalidate stale L2 plane lines
    }
}

// ---------------- launch ----------------------------------------------------

extern "C" void kernel_launch(void* const* d_in, const int* in_sizes, int n_in,
                              void* d_out, int out_size, void* d_ws, size_t ws_size,
                              hipStream_t stream) {
    const float* hyp      = (const float*)d_in[0];   // [3][4]
    const float* rand_mat = (const float*)d_in[1];   // [1500][1500]
    float* out            = (float*)d_out;           // [1500][8][12]

    char* p = (char*)d_ws;
    ushort* Whi  = (ushort*)p; p += (size_t)NPAD * NPAD * 2;
    ushort* Wlo  = (ushort*)p; p += (size_t)NPAD * NPAD * 2;
    ushort* W2hi = (ushort*)p; p += (size_t)NPAD * NPAD * 2;
    ushort* W2lo = (ushort*)p; p += (size_t)NPAD * NPAD * 2;
    ushort* rhiA = (ushort*)p; p += (size_t)BATCH * NPAD * 2;
    ushort* rloA = (ushort*)p; p += (size_t)BATCH * NPAD * 2;
    ushort* rhiB = (ushort*)p; p += (size_t)BATCH * NPAD * 2;
    ushort* rloB = (ushort*)p; p += (size_t)BATCH * NPAD * 2;

    hipFuncSetAttribute((const void*)k_coop,
                        hipFuncAttributeMaxDynamicSharedMemorySize, LDS_BYTES);

    k_weights<<<dim3(NPAD / 256, NPAD), 256, 0, stream>>>(hyp, rand_mat,
                                                          Whi, Wlo, W2hi, W2lo);

    void* args[] = {(void*)&Whi, (void*)&Wlo, (void*)&W2hi, (void*)&W2lo,
                    (void*)&rhiA, (void*)&rloA, (void*)&rhiB, (void*)&rloB,
                    (void*)&out};
    hipLaunchCooperativeKernel((const void*)k_coop, dim3(NWG), dim3(NTHR),
                               args, LDS_BYTES, stream);
}

// Round 7
// 1175.445 us; speedup vs baseline: 4.6959x; 4.6959x over previous
//
#include <hip/hip_runtime.h>
#include <hip/hip_bf16.h>
#include <math.h>

// Problem constants
#define NN      1500
#define NEE     1200
#define NPAD    1536
#define BATCH   96
#define NSTEP   60
#define PI_F    3.14159265358979323846f

// k_step geometry: 192 WGs = 96 i-tiles (16) x 2 batch-halves (48)
// 1024 threads = 16 waves; waves split K 16-ways (96 each = 3 MFMA k-iters)
#define NTHR    1024
#define WAVES   16
#define KSLW    (NPAD / WAVES) // 96
#define BH      48             // batch-half size
#define MFR     3              // m fragments per wave (48/16)

// LDS reduce: 16 slots x [2 outs][16 i][49 pad-b] f32
#define BP      49
#define SLOTF   (2 * 16 * BP)            // 1568 floats
#define LDS_BYTES (WAVES * SLOTF * 4)    // 100352 B (dynamic)

typedef __attribute__((ext_vector_type(8))) short short8b;  // 8 bf16
typedef __attribute__((ext_vector_type(4))) float f32x4;    // MFMA acc

// ---------------- bf16 split helpers ----------------------------------------

__device__ __forceinline__ ushort bf16_rn(float x) {
    unsigned u = __float_as_uint(x);
    unsigned r = (u + 0x7FFFu + ((u >> 16) & 1u)) >> 16;
    return (ushort)r;
}
__device__ __forceinline__ float bf16f(ushort h) {
    return __uint_as_float(((unsigned)h) << 16);
}

// ---------------- phi (Ricciardi LIF transfer) ------------------------------

__device__ __forceinline__ float f_ricci(float x) {
    float z = x / (1.0f + x);
    float t = -z;
    float p = 0.14805913578876898f;
    p = p * t + 0.64290613877355551f;
    p = p * t + 1.0616084849547165f;
    p = p * t + 0.93524391761244940f;
    p = p * t + 0.62718906618071668f;
    p = p * t + 0.32171431660633076f;
    p = p * t + 0.32056016125642045f;
    p = p * t + 0.77373949685442023f;
    p = p * t + 0.22757881388024176f;
    p = p * t;
    return logf(2.0f * x + 1.0f) + p;
}

__device__ __forceinline__ float g_ricci(float x) {
    float z = x / (2.0f + x);
    float num = z * (3.5441754117462949f + z * (-7.0529131065835378f + z * (-56.532378057580381f
        + z * (279.56761105465944f + z * (-520.37554849441472f + z * (456.58245777026514f
        + z * (-155.73340457809226f)))))));
    float den = 1.0f + z * (-4.1357968834226053f + z * (-7.2984226138266743f + z * (98.656602235468327f
        + z * (-334.20436223415163f + z * (601.08633903294185f + z * (-599.58577549598340f
        + z * (277.18420330693891f + z * (-16.445022798669722f))))))));
    return num / den;
}

__device__ __forceinline__ float phi_lif(float mu, float sig, float tau, float tau_ref) {
    float xp = mu / sig;
    float xm = (mu - 20.0f) / sig;
    float r0;
    if (xm > 0.0f) {
        r0 = 1.0f / (f_ricci(xp) - f_ricci(xm));
    } else if (xp > 0.0f) {
        r0 = 1.0f / (f_ricci(xp) + expf(xm * xm) * g_ricci(-xm));
    } else {
        float a = g_ricci(-xm) - expf(xp * xp - xm * xm) * g_ricci(-xp);
        r0 = expf(-xm * xm - logf(a));
    }
    r0 = fmaxf(r0, 1e-30f);
    return 1.0f / (tau_ref + tau / r0);
}

__device__ __forceinline__ float pref_of(int n) {
    const float stepE = 179.99f / 1200.0f;
    const float stepI = 179.99f / 300.0f;
    return (n < NEE) ? (float)n * stepE : (float)(n - NEE) * stepI;
}

// ---------------- kernel 1: build bf16-split weight planes [i][k] -----------

__global__ __launch_bounds__(256) void k_weights(const float* __restrict__ hyp,
        const float* __restrict__ rand_mat,
        ushort* __restrict__ Whi, ushort* __restrict__ Wlo,
        ushort* __restrict__ W2hi, ushort* __restrict__ W2lo) {
    int k = blockIdx.x * 256 + threadIdx.x;   // source neuron (contiguous)
    int i = blockIdx.y;                        // dest neuron
    size_t idx = (size_t)i * NPAD + k;
    if (i >= NN || k >= NN) {
        Whi[idx] = 0; Wlo[idx] = 0; W2hi[idx] = 0; W2lo[idx] = 0;
        return;
    }
    float diff = fabsf(pref_of(i) - pref_of(k));
    int conn = (i >= NEE ? 1 : 0) + 2 * (k >= NEE ? 1 : 0);
    float J  = hyp[conn];
    float P  = hyp[4 + conn];
    float Wp = hyp[8 + conn];
    float dn = 4.0f * (PI_F / 180.0f * Wp) * (PI_F / 180.0f * Wp);
    float z = expf((cosf(2.0f * PI_F / 180.0f * diff) - 1.0f) / dn);
    float x = 32.0f * (P * z - rand_mat[(size_t)i * NN + k]);
    float w = J / (1.0f + expf(-x));
    float w2 = w * w;
    ushort h = bf16_rn(w);
    Whi[idx] = h;  Wlo[idx] = bf16_rn(w - bf16f(h));
    ushort h2 = bf16_rn(w2);
    W2hi[idx] = h2; W2lo[idx] = bf16_rn(w2 - bf16f(h2));
}

// ---------------- kernel 2: mean + zero-init rate state ---------------------

__global__ __launch_bounds__(256) void k_init(float* __restrict__ mean,
                                              float* __restrict__ rate,
                                              ushort* __restrict__ rhiA,
                                              ushort* __restrict__ rloA) {
    int i = blockIdx.x * 256 + threadIdx.x;
    int b = blockIdx.y;                        // batch = c*12 + o
    int c = b / 12, o = b % 12;
    const float contrasts[8] = {0.0f, 0.0432773f, 0.103411f, 0.186966f,
                                0.303066f, 0.464386f, 0.68854f, 1.0f};
    float m = 0.0f;
    if (i < NN) {
        float dth = 15.0f * (float)o - pref_of(i);
        const float dn = 4.0f * (PI_F / 180.0f * 30.0f) * (PI_F / 180.0f * 30.0f);
        m = contrasts[c] * 20.0f * expf((cosf(2.0f * PI_F / 180.0f * dth) - 1.0f) / dn);
    }
    size_t idx = (size_t)b * NPAD + i;
    mean[idx] = m;
    rate[idx] = 0.0f;
    rhiA[idx] = 0;
    rloA[idx] = 0;
}

// ---------------- kernel 3: one full Euler step (fused, no global partials) -
// Grid: 192 WGs = (96 i-tiles of 16) x (2 batch-halves of 48); 1024 thr / 16
// waves (4 waves/SIMD for latency hiding). Wave w: k-slice [w*96, w*96+96).
// 16 waves dump accs to 16 LDS slots -> ONE barrier -> threads sum slots,
// phi + Euler, write next bf16 rate planes (double-buffered).

__global__ __launch_bounds__(NTHR) void k_step(
        const ushort* __restrict__ Whi, const ushort* __restrict__ Wlo,
        const ushort* __restrict__ W2hi, const ushort* __restrict__ W2lo,
        const ushort* __restrict__ rin_hi, const ushort* __restrict__ rin_lo,
        ushort* __restrict__ rout_hi, ushort* __restrict__ rout_lo,
        float* __restrict__ rate, const float* __restrict__ mean,
        float* __restrict__ out, int last)
{
    extern __shared__ float sm[];
    const int tid  = threadIdx.x;
    const int wave = tid >> 6;
    const int lane = tid & 63;
    const int lr   = lane & 15;
    const int lq   = lane >> 4;
    const int bx   = blockIdx.x;
    const int it   = bx % 96;          // bx and bx+96 are 96 apart: same XCD (96%8==0)
    const int bhf  = bx / 96;          // batch half
    const int i0   = it * 16;
    const int b0   = bhf * BH;
    const int kb   = wave * KSLW;

    f32x4 acc1[MFR], acc2[MFR];
#pragma unroll
    for (int m = 0; m < MFR; m++) {
        acc1[m] = (f32x4){0.0f, 0.0f, 0.0f, 0.0f};
        acc2[m] = (f32x4){0.0f, 0.0f, 0.0f, 0.0f};
    }

    const size_t bof = (size_t)(i0 + lr) * NPAD + kb + lq * 8;
#pragma unroll
    for (int kk = 0; kk < KSLW / 32; kk++) {
        const int ko = kk * 32;
        short8b wh  = *(const short8b*)(Whi  + bof + ko);
        short8b wl  = *(const short8b*)(Wlo  + bof + ko);
        short8b w2h = *(const short8b*)(W2hi + bof + ko);
        short8b w2l = *(const short8b*)(W2lo + bof + ko);
#pragma unroll
        for (int m = 0; m < MFR; m++) {
            const size_t aof = (size_t)(b0 + m * 16 + lr) * NPAD + kb + lq * 8 + ko;
            short8b ah = *(const short8b*)(rin_hi + aof);
            short8b al = *(const short8b*)(rin_lo + aof);
            // identical pass set to rounds 4/5 (numerics held constant)
            acc1[m] = __builtin_amdgcn_mfma_f32_16x16x32_bf16(ah, wh,  acc1[m], 0, 0, 0);
            acc1[m] = __builtin_amdgcn_mfma_f32_16x16x32_bf16(ah, wl,  acc1[m], 0, 0, 0);
            acc1[m] = __builtin_amdgcn_mfma_f32_16x16x32_bf16(al, wh,  acc1[m], 0, 0, 0);
            acc2[m] = __builtin_amdgcn_mfma_f32_16x16x32_bf16(ah, w2h, acc2[m], 0, 0, 0);
            acc2[m] = __builtin_amdgcn_mfma_f32_16x16x32_bf16(ah, w2l, acc2[m], 0, 0, 0);
            acc2[m] = __builtin_amdgcn_mfma_f32_16x16x32_bf16(al, w2h, acc2[m], 0, 0, 0);
        }
    }

    // ---- dump accs to own slot; layout [o][i=lr][b padded BP] ---------------
    // C/D mapping: col(i) = lr, row(b within m-frag) = 4*lq + r
    {
        float* sp = sm + wave * SLOTF;
#pragma unroll
        for (int m = 0; m < MFR; m++) {
            float* p1 = sp + lr * BP + m * 16 + 4 * lq;
            float* p2 = p1 + 16 * BP;
            *(f32x4*)p1 = acc1[m];
            *(f32x4*)p2 = acc2[m];
        }
    }
    __syncthreads();

    // ---- sum 16 slots + phi + Euler update for 48b x 16i block --------------
    if (tid < BH * 16) {
        const int c = tid & 15;        // i within tile
        const int b = tid >> 4;        // b within half
        const int ig = i0 + c;
        const int gb = b0 + b;
        const size_t gx = (size_t)gb * NPAD + ig;
        float rn = 0.0f;
        if (ig < NN) {
            float u1 = 0.0f, u2 = 0.0f;
#pragma unroll
            for (int s = 0; s < WAVES; s++) {
                u1 += sm[s * SLOTF + c * BP + b];
                u2 += sm[s * SLOTF + (16 + c) * BP + b];
            }
            float mu = 0.01f * u1 + mean[gx];
            float sg = sqrtf(0.01f * u2 + 25.0f);      // SIG_EXT^2 = 25
            float tr = (ig < NEE) ? 0.005f : 0.001f;
            float Ti = (ig < NEE) ? 100.0f : 200.0f;
            float rr = rate[gx];
            float ph = phi_lif(mu, sg, 0.01f, tr);
            rn = rr + 1e-3f * Ti * (ph - rr);
            rate[gx] = rn;
            if (last) out[(size_t)ig * BATCH + gb] = rn;
        }
        ushort h = bf16_rn(rn);
        rout_hi[gx] = h;
        rout_lo[gx] = bf16_rn(rn - bf16f(h));
    }
}

// ---------------- launch ----------------------------------------------------

extern "C" void kernel_launch(void* const* d_in, const int* in_sizes, int n_in,
                              void* d_out, int out_size, void* d_ws, size_t ws_size,
                              hipStream_t stream) {
    const float* hyp      = (const float*)d_in[0];   // [3][4]
    const float* rand_mat = (const float*)d_in[1];   // [1500][1500]
    float* out            = (float*)d_out;           // [1500][8][12]

    char* p = (char*)d_ws;
    ushort* Whi  = (ushort*)p; p += (size_t)NPAD * NPAD * 2;
    ushort* Wlo  = (ushort*)p; p += (size_t)NPAD * NPAD * 2;
    ushort* W2hi = (ushort*)p; p += (size_t)NPAD * NPAD * 2;
    ushort* W2lo = (ushort*)p; p += (size_t)NPAD * NPAD * 2;
    ushort* rhiA = (ushort*)p; p += (size_t)BATCH * NPAD * 2;
    ushort* rloA = (ushort*)p; p += (size_t)BATCH * NPAD * 2;
    ushort* rhiB = (ushort*)p; p += (size_t)BATCH * NPAD * 2;
    ushort* rloB = (ushort*)p; p += (size_t)BATCH * NPAD * 2;
    float*  mean = (float*)p;  p += (size_t)BATCH * NPAD * 4;
    float*  rate = (float*)p;  p += (size_t)BATCH * NPAD * 4;

    hipFuncSetAttribute((const void*)k_step,
                        hipFuncAttributeMaxDynamicSharedMemorySize, LDS_BYTES);

    k_weights<<<dim3(NPAD / 256, NPAD), 256, 0, stream>>>(hyp, rand_mat, Whi, Wlo, W2hi, W2lo);
    k_init<<<dim3(NPAD / 256, BATCH), 256, 0, stream>>>(mean, rate, rhiA, rloA);

    for (int s = 0; s < NSTEP; s++) {
        const ushort* ih = (s & 1) ? rhiB : rhiA;
        const ushort* il = (s & 1) ? rloB : rloA;
        ushort* oh = (s & 1) ? rhiA : rhiB;
        ushort* ol = (s & 1) ? rloA : rloB;
        k_step<<<dim3(192), dim3(NTHR), LDS_BYTES, stream>>>(
            Whi, Wlo, W2hi, W2lo, ih, il, oh, ol, rate, mean, out,
            (s == NSTEP - 1) ? 1 : 0);
    }
}